// Round 1
// baseline (138.682 us; speedup 1.0000x reference)
//
#include <hip/hip_runtime.h>
#include <hip/hip_bf16.h>
#include <math.h>

#define T_TOK 2048
#define DIM 512
#define HID 1024
#define NE 8
#define CAP 1024   // per-expert pair capacity (actual ~512 at seed-0 routing)

#define ROUT_BLKS 128
#define ZERO_BLKS 256   // zero out[] (4 MB) concurrently with router

typedef __attribute__((ext_vector_type(8))) short short8;
typedef __attribute__((ext_vector_type(4))) float floatx4;

__device__ __forceinline__ unsigned short f2bf_bits(float f) {
    __hip_bfloat16 h = __float2bfloat16(f);
    return *reinterpret_cast<unsigned short*>(&h);
}

// async global->LDS: 64 lanes x 16B = 1 KB; LDS dst = wave-uniform base + lane*16
__device__ __forceinline__ void gl2lds(const unsigned short* g, unsigned short* l) {
    __builtin_amdgcn_global_load_lds(
        (const __attribute__((address_space(1))) unsigned int*)g,
        (__attribute__((address_space(3))) unsigned int*)l, 16, 0, 0);
}

// LDS frag read: packed [row][128] shorts (BK=128), 16-B granule kg of row r
// stored at kg^(r&7) (XOR permutes low 3 bits within each 8-granule half)
__device__ __forceinline__ short8 frag(const unsigned short* s, int row, int kg) {
    return *reinterpret_cast<const short8*>(s + row * 128 + (((kg) ^ (row & 7)) << 3));
}

// stage T rows (k-slice of 128 = 256 B/row) from bf16 row-major global into
// packed swizzled LDS; one gl2lds covers 4 rows (lane>>4) x 16 granules (lane&15)
template<int T>
__device__ __forceinline__ void stage_tile(const unsigned short* src, size_t RS,
                                           int k0, unsigned short* lds,
                                           int wave, int lane) {
    int ro = lane >> 4, gr = lane & 15;
#pragma unroll
    for (int i = wave; i < T / 4; i += 4) {
        int r = i * 4 + ro;
        gl2lds(src + (size_t)r * RS + k0 + (((gr ^ (r & 7)) << 3)),
               lds + i * 512);
    }
}

// stage R rows x 128 k of an f32 row-major source into the SAME swizzled bf16
// LDS layout (inline cast: removes the separate weight-cast pass entirely).
// Per thread: granule gr (8 floats = 2 float4 loads -> 1 ds_write_b128).
template<int R>
__device__ __forceinline__ void stage_f32(const float* src, size_t RS, int k0,
                                          unsigned short* lds, int tid) {
    int gr = tid & 15, r0 = tid >> 4;
#pragma unroll 4
    for (int i = 0; i < R / 16; i++) {
        int r = r0 + i * 16;
        const float4* s = reinterpret_cast<const float4*>(src + (size_t)r * RS + k0 + gr * 8);
        float4 va = s[0], vb = s[1];
        short8 o;
        o[0] = (short)f2bf_bits(va.x); o[1] = (short)f2bf_bits(va.y);
        o[2] = (short)f2bf_bits(va.z); o[3] = (short)f2bf_bits(va.w);
        o[4] = (short)f2bf_bits(vb.x); o[5] = (short)f2bf_bits(vb.y);
        o[6] = (short)f2bf_bits(vb.z); o[7] = (short)f2bf_bits(vb.w);
        *reinterpret_cast<short8*>(lds + r * 128 + ((gr ^ (r & 7)) << 3)) = o;
    }
}

// ---------------- prep: router+gather (blocks 0..127) | zero out ----------------
__global__ __launch_bounds__(256)
void prep(const float* __restrict__ x, const float* __restrict__ wr,
          const float* __restrict__ br,
          unsigned short* __restrict__ xg, int* __restrict__ counts,
          int* __restrict__ tokOf, float* __restrict__ wOf,
          float* __restrict__ out, float* __restrict__ logits_out) {
    int bx = blockIdx.x;
    int tid = threadIdx.x;
    if (bx >= ROUT_BLKS) {
        // zero the combine target (gemm2 scatters with atomicAdd)
        float4 z; z.x = z.y = z.z = z.w = 0.f;
        int base = (bx - ROUT_BLKS) * 256 + tid;   // 65536 threads
#pragma unroll
        for (int rep = 0; rep < 4; rep++)
            reinterpret_cast<float4*>(out)[base + rep * 65536] = z;
        return;
    }
    // router: 128 blocks x 16 tokens; wave per token, 4 iterations
    int wave = tid >> 6, lane = tid & 63;
    for (int it = 0; it < 4; it++) {
        int t = bx * 16 + it * 4 + wave;
        const float4* xr = reinterpret_cast<const float4*>(x + (size_t)t * DIM);
        float4 xa = xr[lane * 2], xc = xr[lane * 2 + 1];
        short8 o;
        o[0] = (short)f2bf_bits(xa.x); o[1] = (short)f2bf_bits(xa.y);
        o[2] = (short)f2bf_bits(xa.z); o[3] = (short)f2bf_bits(xa.w);
        o[4] = (short)f2bf_bits(xc.x); o[5] = (short)f2bf_bits(xc.y);
        o[6] = (short)f2bf_bits(xc.z); o[7] = (short)f2bf_bits(xc.w);
        float p[NE];
#pragma unroll
        for (int e = 0; e < NE; e++) {
            const float4* wre = reinterpret_cast<const float4*>(wr + e * DIM);
            float4 wa = wre[lane * 2], wc = wre[lane * 2 + 1];
            p[e] = xa.x * wa.x + xa.y * wa.y + xa.z * wa.z + xa.w * wa.w
                 + xc.x * wc.x + xc.y * wc.y + xc.z * wc.z + xc.w * wc.w;
        }
#pragma unroll
        for (int e = 0; e < NE; e++) {
#pragma unroll
            for (int off = 32; off >= 1; off >>= 1)
                p[e] += __shfl_xor(p[e], off, 64);
        }
        int slot1 = 0, slot2 = 0;
        if (lane == 0) {
            float l[NE];
#pragma unroll
            for (int e = 0; e < NE; e++) {
                l[e] = p[e] + br[e];
                logits_out[(size_t)t * NE + e] = l[e];
            }
            int e1 = 0;
#pragma unroll
            for (int e = 1; e < NE; e++) if (l[e] > l[e1]) e1 = e;
            int es = -1;
#pragma unroll
            for (int e = 0; e < NE; e++) {
                if (e == e1) continue;
                if (es < 0 || l[e] > l[es]) es = e;
            }
            float z = expf(l[es] - l[e1]);
            float inv = 1.f / (1.f + z);
            int pos1 = atomicAdd(&counts[e1 * 16], 1);
            if (pos1 > CAP - 1) pos1 = CAP - 1;
            int pos2 = atomicAdd(&counts[es * 16], 1);
            if (pos2 > CAP - 1) pos2 = CAP - 1;
            slot1 = e1 * CAP + pos1;
            slot2 = es * CAP + pos2;
            tokOf[slot1] = t; wOf[slot1] = inv;
            tokOf[slot2] = t; wOf[slot2] = z * inv;
        }
        slot1 = __shfl(slot1, 0);
        slot2 = __shfl(slot2, 0);
        *reinterpret_cast<short8*>(xg + (size_t)slot1 * DIM + lane * 8) = o;
        *reinterpret_cast<short8*>(xg + (size_t)slot2 * DIM + lane * 8) = o;
    }
}

// ---------------- GEMM1: H = gelu(Xg @ W1^T), per expert ----------------
// Block 64m x 128n, K=512 in 4 phases of BK=128. 4 waves (2x2), 48 KB LDS.
// B operand read directly from f32 w1 (inline cast while staging).
__global__ __launch_bounds__(256, 3)
void gemm1(const unsigned short* __restrict__ xg,
           const float* __restrict__ w1,
           const int* __restrict__ counts,
           unsigned short* __restrict__ Hb) {
    int bx = blockIdx.x;
    int e = bx & 7;                       // XCD affinity
    int rest = bx >> 3;
    int n0 = (rest & 7) * 128;
    int m0 = (rest >> 3) * 64;
    int cnt = counts[e * 16]; if (cnt > CAP) cnt = CAP;
    if (m0 >= cnt) return;

    __shared__ __align__(16) unsigned short s_a[64 * 128];    // 16 KB
    __shared__ __align__(16) unsigned short s_b[128 * 128];   // 32 KB

    int tid = threadIdx.x, wave = tid >> 6, lane = tid & 63;
    int g = lane >> 4, ln = lane & 15;
    int wm = wave & 1, wn = wave >> 1;

    const unsigned short* asrc = xg + (size_t)(e * CAP + m0) * DIM;
    const float* bsrc = w1 + (size_t)(e * HID + n0) * DIM;

    floatx4 acc[2][4];
#pragma unroll
    for (int mf = 0; mf < 2; mf++)
#pragma unroll
        for (int nf = 0; nf < 4; nf++) acc[mf][nf] = (floatx4){0.f, 0.f, 0.f, 0.f};

    for (int ph = 0; ph < 4; ph++) {
        int k0 = ph * 128;
        stage_tile<64>(asrc, DIM, k0, s_a, wave, lane);   // async bf16 A
        stage_f32<128>(bsrc, DIM, k0, s_b, tid);          // f32->bf16 B
        __syncthreads();
#pragma unroll
        for (int ks = 0; ks < 4; ks++) {
            short8 a0 = frag(s_a, wm * 32 + ln, ks * 4 + g);
            short8 a1 = frag(s_a, wm * 32 + 16 + ln, ks * 4 + g);
#pragma unroll
            for (int nf = 0; nf < 4; nf++) {
                short8 b = frag(s_b, wn * 64 + nf * 16 + ln, ks * 4 + g);
                acc[0][nf] = __builtin_amdgcn_mfma_f32_16x16x32_bf16(a0, b, acc[0][nf], 0, 0, 0);
                acc[1][nf] = __builtin_amdgcn_mfma_f32_16x16x32_bf16(a1, b, acc[1][nf], 0, 0, 0);
            }
        }
        __syncthreads();
    }
#pragma unroll
    for (int mf = 0; mf < 2; mf++)
#pragma unroll
        for (int nf = 0; nf < 4; nf++)
#pragma unroll
            for (int r = 0; r < 4; r++) {
                int lr = wm * 32 + mf * 16 + g * 4 + r;
                int col = n0 + wn * 64 + nf * 16 + ln;
                float v = acc[mf][nf][r];
                float gv = 0.5f * v * (1.f + erff(v * 0.70710678118f));
                Hb[(size_t)(e * CAP + m0 + lr) * HID + col] = f2bf_bits(gv);
            }
}

// ---------------- GEMM2: out += w * (H @ W2^T), fused combine via atomics ----------------
// Block 64m x 128n, kv-split (two K halves of 512, 4 phases each).
// B operand read directly from f32 w2. Epilogue scatters to out[tok] with atomicAdd.
__global__ __launch_bounds__(256, 3)
void gemm2(const unsigned short* __restrict__ Hb,
           const float* __restrict__ w2,
           const int* __restrict__ counts,
           const int* __restrict__ tokOf, const float* __restrict__ wOf,
           float* __restrict__ out) {
    int bx = blockIdx.x;
    int e = bx & 7;
    int rest = bx >> 3;
    int n0 = (rest & 3) * 128;
    int kv = (rest >> 2) & 1;
    int m0 = (rest >> 3) * 64;
    int cnt = counts[e * 16]; if (cnt > CAP) cnt = CAP;
    if (m0 >= cnt) return;

    __shared__ __align__(16) unsigned short s_a[64 * 128];
    __shared__ __align__(16) unsigned short s_b[128 * 128];

    int tid = threadIdx.x, wave = tid >> 6, lane = tid & 63;
    int g = lane >> 4, ln = lane & 15;
    int wm = wave & 1, wn = wave >> 1;

    const unsigned short* asrc = Hb + (size_t)(e * CAP + m0) * HID;
    const float* bsrc = w2 + (size_t)(e * DIM + n0) * HID;

    floatx4 acc[2][4];
#pragma unroll
    for (int mf = 0; mf < 2; mf++)
#pragma unroll
        for (int nf = 0; nf < 4; nf++) acc[mf][nf] = (floatx4){0.f, 0.f, 0.f, 0.f};

    for (int ph = 0; ph < 4; ph++) {
        int k0 = kv * 512 + ph * 128;
        stage_tile<64>(asrc, HID, k0, s_a, wave, lane);   // async bf16 A (Hb)
        stage_f32<128>(bsrc, HID, k0, s_b, tid);          // f32->bf16 B (w2)
        __syncthreads();
#pragma unroll
        for (int ks = 0; ks < 4; ks++) {
            short8 a0 = frag(s_a, wm * 32 + ln, ks * 4 + g);
            short8 a1 = frag(s_a, wm * 32 + 16 + ln, ks * 4 + g);
#pragma unroll
            for (int nf = 0; nf < 4; nf++) {
                short8 b = frag(s_b, wn * 64 + nf * 16 + ln, ks * 4 + g);
                acc[0][nf] = __builtin_amdgcn_mfma_f32_16x16x32_bf16(a0, b, acc[0][nf], 0, 0, 0);
                acc[1][nf] = __builtin_amdgcn_mfma_f32_16x16x32_bf16(a1, b, acc[1][nf], 0, 0, 0);
            }
        }
        __syncthreads();
    }
    // fused combine: out[tok, col] += w * y  (2 experts x 2 kv halves per element)
#pragma unroll
    for (int mf = 0; mf < 2; mf++)
#pragma unroll
        for (int r = 0; r < 4; r++) {
            int lr = wm * 32 + mf * 16 + g * 4 + r;
            int row = m0 + lr;
            if (row >= cnt) continue;           // garbage pad rows: skip
            int slot = e * CAP + row;
            int t = tokOf[slot];
            float w = wOf[slot];
            float* orow = out + (size_t)t * DIM + n0 + wn * 64 + ln;
#pragma unroll
            for (int nf = 0; nf < 4; nf++)
                atomicAdd(orow + nf * 16, w * acc[mf][nf][r]);
        }
}

extern "C" void kernel_launch(void* const* d_in, const int* in_sizes, int n_in,
                              void* d_out, int out_size, void* d_ws, size_t ws_size,
                              hipStream_t stream) {
    const float* x  = (const float*)d_in[0];
    const float* wr = (const float*)d_in[1];
    const float* br = (const float*)d_in[2];
    const float* w1 = (const float*)d_in[3];
    const float* w2 = (const float*)d_in[4];
    float* out = (float*)d_out;
    float* logits_out = out + (size_t)T_TOK * DIM;

    char* ws = (char*)d_ws;
    int*   counts = (int*)ws;                              // 512 B (x16 padded)
    int*   tokOf  = (int*)(ws + 4096);                     // 32 KB
    float* wOf    = (float*)(ws + 40960);                  // 32 KB
    unsigned short* xg = (unsigned short*)(ws + 131072);   // 8 MB
    unsigned short* Hb = (unsigned short*)(ws + 8519680);  // 16 MB (ends ~25 MB)

    hipMemsetAsync(counts, 0, 512, stream);

    prep<<<ROUT_BLKS + ZERO_BLKS, 256, 0, stream>>>(
        x, wr, br, xg, counts, tokOf, wOf, out, logits_out);

    gemm1<<<NE * 16 * 8, 256, 0, stream>>>(xg, w1, counts, Hb);

    gemm2<<<NE * 16 * 2 * 4, 256, 0, stream>>>(Hb, w2, counts, tokOf, wOf, out);
}

// Round 2
// 132.963 us; speedup vs baseline: 1.0430x; 1.0430x over previous
//
#include <hip/hip_runtime.h>
#include <hip/hip_bf16.h>
#include <math.h>

#define T_TOK 2048
#define DIM 512
#define HID 1024
#define NE 8
#define CAP 1024   // per-expert pair capacity (actual ~512 at seed-0 routing)

#define ROUT_BLKS 128
#define CAST_BLKS 2048   // 2*1048576 float4 / (256 thr * 4 per thread)
#define ZERO_BLKS 256    // zero out[] (4.19 MB) for gemm2's atomic combine

typedef __attribute__((ext_vector_type(8))) short short8;
typedef __attribute__((ext_vector_type(4))) float floatx4;

__device__ __forceinline__ unsigned short f2bf_bits(float f) {
    __hip_bfloat16 h = __float2bfloat16(f);
    return *reinterpret_cast<unsigned short*>(&h);
}

// async global->LDS: 64 lanes x 16B = 1 KB; LDS dst = wave-uniform base + lane*16
__device__ __forceinline__ void gl2lds(const unsigned short* g, unsigned short* l) {
    __builtin_amdgcn_global_load_lds(
        (const __attribute__((address_space(1))) unsigned int*)g,
        (__attribute__((address_space(3))) unsigned int*)l, 16, 0, 0);
}

// LDS frag read: packed [row][128] shorts (BK=128), 16-B granule kg of row r
// stored at kg^(r&7) (XOR permutes low 3 bits within each 8-granule half)
__device__ __forceinline__ short8 frag(const unsigned short* s, int row, int kg) {
    return *reinterpret_cast<const short8*>(s + row * 128 + (((kg) ^ (row & 7)) << 3));
}

// stage T rows (k-slice of 128 = 256 B/row) from row-major global into packed
// swizzled LDS; one gl2lds covers 4 rows (lane>>4) x 16 granules (lane&15)
template<int T>
__device__ __forceinline__ void stage_tile(const unsigned short* src, size_t RS,
                                           int k0, unsigned short* lds,
                                           int wave, int lane) {
    int ro = lane >> 4, gr = lane & 15;
#pragma unroll
    for (int i = wave; i < T / 4; i += 4) {
        int r = i * 4 + ro;
        gl2lds(src + (size_t)r * RS + k0 + (((gr ^ (r & 7)) << 3)),
               lds + i * 512);
    }
}

// ---------------- prep: router+gather | weight cast | zero out ----------------
__global__ __launch_bounds__(256)
void prep(const float* __restrict__ x, const float* __restrict__ wr,
          const float* __restrict__ br,
          const float* __restrict__ w1, const float* __restrict__ w2,
          unsigned short* __restrict__ w1b, unsigned short* __restrict__ w2b,
          unsigned short* __restrict__ xg, int* __restrict__ counts,
          int* __restrict__ tokOf, float* __restrict__ wOf,
          float* __restrict__ out, float* __restrict__ logits_out) {
    int bx = blockIdx.x;
    int tid = threadIdx.x;
    if (bx >= ROUT_BLKS + CAST_BLKS) {
        // zero the combine target (gemm2 scatters with atomicAdd)
        float4 z; z.x = z.y = z.z = z.w = 0.f;
        int base = (bx - ROUT_BLKS - CAST_BLKS) * 1024 + tid;
#pragma unroll
        for (int rep = 0; rep < 4; rep++)
            reinterpret_cast<float4*>(out)[base + rep * 256] = z;
        return;
    }
    if (bx >= ROUT_BLKS) {
        // weight cast: 4 float4 per thread
        const int n1 = NE * HID * DIM / 4;
        int base = (bx - ROUT_BLKS) * 1024 + tid;
#pragma unroll
        for (int rep = 0; rep < 4; rep++) {
            int i = base + rep * 256;
            const float* s = (i < n1) ? w1 : w2;
            unsigned short* d = (i < n1) ? w1b : w2b;
            int j = (i < n1) ? i : i - n1;
            float4 v = reinterpret_cast<const float4*>(s)[j];
            ushort4 o;
            o.x = f2bf_bits(v.x); o.y = f2bf_bits(v.y);
            o.z = f2bf_bits(v.z); o.w = f2bf_bits(v.w);
            reinterpret_cast<ushort4*>(d)[j] = o;
        }
        return;
    }
    // router: 128 blocks x 16 tokens; wave per token, 4 iterations
    int wave = tid >> 6, lane = tid & 63;
    for (int it = 0; it < 4; it++) {
        int t = bx * 16 + it * 4 + wave;
        const float4* xr = reinterpret_cast<const float4*>(x + (size_t)t * DIM);
        float4 xa = xr[lane * 2], xc = xr[lane * 2 + 1];
        short8 o;
        o[0] = (short)f2bf_bits(xa.x); o[1] = (short)f2bf_bits(xa.y);
        o[2] = (short)f2bf_bits(xa.z); o[3] = (short)f2bf_bits(xa.w);
        o[4] = (short)f2bf_bits(xc.x); o[5] = (short)f2bf_bits(xc.y);
        o[6] = (short)f2bf_bits(xc.z); o[7] = (short)f2bf_bits(xc.w);
        float p[NE];
#pragma unroll
        for (int e = 0; e < NE; e++) {
            const float4* wre = reinterpret_cast<const float4*>(wr + e * DIM);
            float4 wa = wre[lane * 2], wc = wre[lane * 2 + 1];
            p[e] = xa.x * wa.x + xa.y * wa.y + xa.z * wa.z + xa.w * wa.w
                 + xc.x * wc.x + xc.y * wc.y + xc.z * wc.z + xc.w * wc.w;
        }
#pragma unroll
        for (int e = 0; e < NE; e++) {
#pragma unroll
            for (int off = 32; off >= 1; off >>= 1)
                p[e] += __shfl_xor(p[e], off, 64);
        }
        int slot1 = 0, slot2 = 0;
        if (lane == 0) {
            float l[NE];
#pragma unroll
            for (int e = 0; e < NE; e++) {
                l[e] = p[e] + br[e];
                logits_out[(size_t)t * NE + e] = l[e];
            }
            int e1 = 0;
#pragma unroll
            for (int e = 1; e < NE; e++) if (l[e] > l[e1]) e1 = e;
            int es = -1;
#pragma unroll
            for (int e = 0; e < NE; e++) {
                if (e == e1) continue;
                if (es < 0 || l[e] > l[es]) es = e;
            }
            float z = expf(l[es] - l[e1]);
            float inv = 1.f / (1.f + z);
            int pos1 = atomicAdd(&counts[e1 * 16], 1);
            if (pos1 > CAP - 1) pos1 = CAP - 1;
            int pos2 = atomicAdd(&counts[es * 16], 1);
            if (pos2 > CAP - 1) pos2 = CAP - 1;
            slot1 = e1 * CAP + pos1;
            slot2 = es * CAP + pos2;
            tokOf[slot1] = t; wOf[slot1] = inv;
            tokOf[slot2] = t; wOf[slot2] = z * inv;
        }
        slot1 = __shfl(slot1, 0);
        slot2 = __shfl(slot2, 0);
        *reinterpret_cast<short8*>(xg + (size_t)slot1 * DIM + lane * 8) = o;
        *reinterpret_cast<short8*>(xg + (size_t)slot2 * DIM + lane * 8) = o;
    }
}

// ---------------- GEMM1: H = gelu(Xg @ W1^T), per expert ----------------
// Block 64m x 128n, K=512 in 4 phases of BK=128. 4 waves (2x2), 48 KB LDS.
__global__ __launch_bounds__(256, 3)
void gemm1(const unsigned short* __restrict__ xg,
           const unsigned short* __restrict__ w1b,
           const int* __restrict__ counts,
           unsigned short* __restrict__ Hb) {
    int bx = blockIdx.x;
    int e = bx & 7;                       // XCD affinity
    int rest = bx >> 3;
    int n0 = (rest & 7) * 128;
    int m0 = (rest >> 3) * 64;
    int cnt = counts[e * 16]; if (cnt > CAP) cnt = CAP;
    if (m0 >= cnt) return;

    __shared__ __align__(16) unsigned short s_a[64 * 128];    // 16 KB
    __shared__ __align__(16) unsigned short s_b[128 * 128];   // 32 KB

    int tid = threadIdx.x, wave = tid >> 6, lane = tid & 63;
    int g = lane >> 4, ln = lane & 15;
    int wm = wave & 1, wn = wave >> 1;

    const unsigned short* asrc = xg + (size_t)(e * CAP + m0) * DIM;
    const unsigned short* bsrc = w1b + (size_t)(e * HID + n0) * DIM;

    floatx4 acc[2][4];
#pragma unroll
    for (int mf = 0; mf < 2; mf++)
#pragma unroll
        for (int nf = 0; nf < 4; nf++) acc[mf][nf] = (floatx4){0.f, 0.f, 0.f, 0.f};

    for (int ph = 0; ph < 4; ph++) {
        int k0 = ph * 128;
        stage_tile<64>(asrc, DIM, k0, s_a, wave, lane);
        stage_tile<128>(bsrc, DIM, k0, s_b, wave, lane);
        __syncthreads();
#pragma unroll
        for (int ks = 0; ks < 4; ks++) {
            short8 a0 = frag(s_a, wm * 32 + ln, ks * 4 + g);
            short8 a1 = frag(s_a, wm * 32 + 16 + ln, ks * 4 + g);
#pragma unroll
            for (int nf = 0; nf < 4; nf++) {
                short8 b = frag(s_b, wn * 64 + nf * 16 + ln, ks * 4 + g);
                acc[0][nf] = __builtin_amdgcn_mfma_f32_16x16x32_bf16(a0, b, acc[0][nf], 0, 0, 0);
                acc[1][nf] = __builtin_amdgcn_mfma_f32_16x16x32_bf16(a1, b, acc[1][nf], 0, 0, 0);
            }
        }
        __syncthreads();
    }
#pragma unroll
    for (int mf = 0; mf < 2; mf++)
#pragma unroll
        for (int nf = 0; nf < 4; nf++)
#pragma unroll
            for (int r = 0; r < 4; r++) {
                int lr = wm * 32 + mf * 16 + g * 4 + r;
                int col = n0 + wn * 64 + nf * 16 + ln;
                float v = acc[mf][nf][r];
                float gv = 0.5f * v * (1.f + erff(v * 0.70710678118f));
                Hb[(size_t)(e * CAP + m0 + lr) * HID + col] = f2bf_bits(gv);
            }
}

// ---------------- GEMM2: out += w * (H @ W2^T), fused combine via atomics ----------------
// Block 64m x 128n, kv-split (two K halves of 512, 4 phases each).
// Epilogue scatters to out[tok] with atomicAdd (replaces ybuf + combine kernel).
__global__ __launch_bounds__(256, 3)
void gemm2(const unsigned short* __restrict__ Hb,
           const unsigned short* __restrict__ w2b,
           const int* __restrict__ counts,
           const int* __restrict__ tokOf, const float* __restrict__ wOf,
           float* __restrict__ out) {
    int bx = blockIdx.x;
    int e = bx & 7;
    int rest = bx >> 3;
    int n0 = (rest & 3) * 128;
    int kv = (rest >> 2) & 1;
    int m0 = (rest >> 3) * 64;
    int cnt = counts[e * 16]; if (cnt > CAP) cnt = CAP;
    if (m0 >= cnt) return;

    __shared__ __align__(16) unsigned short s_a[64 * 128];
    __shared__ __align__(16) unsigned short s_b[128 * 128];

    int tid = threadIdx.x, wave = tid >> 6, lane = tid & 63;
    int g = lane >> 4, ln = lane & 15;
    int wm = wave & 1, wn = wave >> 1;

    const unsigned short* asrc = Hb + (size_t)(e * CAP + m0) * HID;
    const unsigned short* bsrc = w2b + (size_t)(e * DIM + n0) * HID;

    floatx4 acc[2][4];
#pragma unroll
    for (int mf = 0; mf < 2; mf++)
#pragma unroll
        for (int nf = 0; nf < 4; nf++) acc[mf][nf] = (floatx4){0.f, 0.f, 0.f, 0.f};

    for (int ph = 0; ph < 4; ph++) {
        int k0 = kv * 512 + ph * 128;
        stage_tile<64>(asrc, HID, k0, s_a, wave, lane);
        stage_tile<128>(bsrc, HID, k0, s_b, wave, lane);
        __syncthreads();
#pragma unroll
        for (int ks = 0; ks < 4; ks++) {
            short8 a0 = frag(s_a, wm * 32 + ln, ks * 4 + g);
            short8 a1 = frag(s_a, wm * 32 + 16 + ln, ks * 4 + g);
#pragma unroll
            for (int nf = 0; nf < 4; nf++) {
                short8 b = frag(s_b, wn * 64 + nf * 16 + ln, ks * 4 + g);
                acc[0][nf] = __builtin_amdgcn_mfma_f32_16x16x32_bf16(a0, b, acc[0][nf], 0, 0, 0);
                acc[1][nf] = __builtin_amdgcn_mfma_f32_16x16x32_bf16(a1, b, acc[1][nf], 0, 0, 0);
            }
        }
        __syncthreads();
    }
    // fused combine: out[tok, col] += w * y  (2 experts x 2 kv halves per element)
#pragma unroll
    for (int mf = 0; mf < 2; mf++)
#pragma unroll
        for (int r = 0; r < 4; r++) {
            int lr = wm * 32 + mf * 16 + g * 4 + r;
            int row = m0 + lr;
            if (row >= cnt) continue;           // pad rows: garbage tokOf, skip
            int slot = e * CAP + row;
            int t = tokOf[slot];
            float w = wOf[slot];
            float* orow = out + (size_t)t * DIM + n0 + wn * 64 + ln;
#pragma unroll
            for (int nf = 0; nf < 4; nf++)
                atomicAdd(orow + nf * 16, w * acc[mf][nf][r]);
        }
}

extern "C" void kernel_launch(void* const* d_in, const int* in_sizes, int n_in,
                              void* d_out, int out_size, void* d_ws, size_t ws_size,
                              hipStream_t stream) {
    const float* x  = (const float*)d_in[0];
    const float* wr = (const float*)d_in[1];
    const float* br = (const float*)d_in[2];
    const float* w1 = (const float*)d_in[3];
    const float* w2 = (const float*)d_in[4];
    float* out = (float*)d_out;
    float* logits_out = out + (size_t)T_TOK * DIM;

    char* ws = (char*)d_ws;
    int*   counts = (int*)ws;                               // 512 B (x16 padded)
    int*   tokOf  = (int*)(ws + 4096);                      // 32 KB
    float* wOf    = (float*)(ws + 40960);                   // 32 KB
    unsigned short* xg  = (unsigned short*)(ws + 131072);   // 8.4 MB
    unsigned short* w1b = (unsigned short*)(ws + 8519680);  // 8.4 MB
    unsigned short* w2b = (unsigned short*)(ws + 16908288); // 8.4 MB
    unsigned short* Hb  = (unsigned short*)(ws + 25296896); // 16.8 MB (ends ~42 MB)

    hipMemsetAsync(counts, 0, 512, stream);

    prep<<<ROUT_BLKS + CAST_BLKS + ZERO_BLKS, 256, 0, stream>>>(
        x, wr, br, w1, w2, w1b, w2b, xg, counts, tokOf, wOf, out, logits_out);

    gemm1<<<NE * 16 * 8, 256, 0, stream>>>(xg, w1b, counts, Hb);

    gemm2<<<NE * 16 * 2 * 4, 256, 0, stream>>>(Hb, w2b, counts, tokOf, wOf, out);
}

// Round 3
// 127.570 us; speedup vs baseline: 1.0871x; 1.0423x over previous
//
#include <hip/hip_runtime.h>
#include <hip/hip_bf16.h>
#include <math.h>

#define T_TOK 2048
#define DIM 512
#define HID 1024
#define NE 8
#define CAP 1024   // per-expert pair capacity (actual ~512 at seed-0 routing)

#define ROUT_BLKS 128
#define CAST1_BLKS 1024   // w1 cast: 1048576 float4 / (256 thr * 4 per thread)
#define GEMM1_BLKS (NE * 16 * 8)
#define CAST2_BLKS 256    // w2 cast inside gemm1 grid: 1048576 float4 / (256 thr * 16)

typedef __attribute__((ext_vector_type(8))) short short8;
typedef __attribute__((ext_vector_type(4))) float floatx4;

__device__ __forceinline__ unsigned short f2bf_bits(float f) {
    __hip_bfloat16 h = __float2bfloat16(f);
    return *reinterpret_cast<unsigned short*>(&h);
}

// async global->LDS: 64 lanes x 16B = 1 KB; LDS dst = wave-uniform base + lane*16
__device__ __forceinline__ void gl2lds(const unsigned short* g, unsigned short* l) {
    __builtin_amdgcn_global_load_lds(
        (const __attribute__((address_space(1))) unsigned int*)g,
        (__attribute__((address_space(3))) unsigned int*)l, 16, 0, 0);
}

// LDS frag read: packed [row][128] shorts (BK=128), 16-B granule kg of row r
// stored at kg^(r&7) (XOR permutes low 3 bits within each 8-granule half)
__device__ __forceinline__ short8 frag(const unsigned short* s, int row, int kg) {
    return *reinterpret_cast<const short8*>(s + row * 128 + (((kg) ^ (row & 7)) << 3));
}

// stage T rows (k-slice of 128 = 256 B/row) from row-major global into packed
// swizzled LDS; one gl2lds covers 4 rows (lane>>4) x 16 granules (lane&15)
template<int T>
__device__ __forceinline__ void stage_tile(const unsigned short* src, size_t RS,
                                           int k0, unsigned short* lds,
                                           int wave, int lane) {
    int ro = lane >> 4, gr = lane & 15;
#pragma unroll
    for (int i = wave; i < T / 4; i += 4) {
        int r = i * 4 + ro;
        gl2lds(src + (size_t)r * RS + k0 + (((gr ^ (r & 7)) << 3)),
               lds + i * 512);
    }
}

// ---------------- prep: router+gather (blocks 0..127) | w1 cast ----------------
// w2 cast is deferred into gemm1's grid tail (overlaps with gemm1 MFMA work).
__global__ __launch_bounds__(256)
void prep(const float* __restrict__ x, const float* __restrict__ wr,
          const float* __restrict__ br,
          const float* __restrict__ w1,
          unsigned short* __restrict__ w1b,
          unsigned short* __restrict__ xg, int* __restrict__ counts,
          int2* __restrict__ pairSlot, float2* __restrict__ pw,
          float* __restrict__ logits_out) {
    int bx = blockIdx.x;
    int tid = threadIdx.x;
    if (bx >= ROUT_BLKS) {
        // w1 cast: 4 float4 per thread
        int base = (bx - ROUT_BLKS) * 1024 + tid;
#pragma unroll
        for (int rep = 0; rep < 4; rep++) {
            int j = base + rep * 256;
            float4 v = reinterpret_cast<const float4*>(w1)[j];
            ushort4 o;
            o.x = f2bf_bits(v.x); o.y = f2bf_bits(v.y);
            o.z = f2bf_bits(v.z); o.w = f2bf_bits(v.w);
            reinterpret_cast<ushort4*>(w1b)[j] = o;
        }
        return;
    }
    // router: 128 blocks x 16 tokens; wave per token, 4 iterations
    int wave = tid >> 6, lane = tid & 63;
    for (int it = 0; it < 4; it++) {
        int t = bx * 16 + it * 4 + wave;
        const float4* xr = reinterpret_cast<const float4*>(x + (size_t)t * DIM);
        float4 xa = xr[lane * 2], xc = xr[lane * 2 + 1];
        short8 o;
        o[0] = (short)f2bf_bits(xa.x); o[1] = (short)f2bf_bits(xa.y);
        o[2] = (short)f2bf_bits(xa.z); o[3] = (short)f2bf_bits(xa.w);
        o[4] = (short)f2bf_bits(xc.x); o[5] = (short)f2bf_bits(xc.y);
        o[6] = (short)f2bf_bits(xc.z); o[7] = (short)f2bf_bits(xc.w);
        float p[NE];
#pragma unroll
        for (int e = 0; e < NE; e++) {
            const float4* wre = reinterpret_cast<const float4*>(wr + e * DIM);
            float4 wa = wre[lane * 2], wc = wre[lane * 2 + 1];
            p[e] = xa.x * wa.x + xa.y * wa.y + xa.z * wa.z + xa.w * wa.w
                 + xc.x * wc.x + xc.y * wc.y + xc.z * wc.z + xc.w * wc.w;
        }
#pragma unroll
        for (int e = 0; e < NE; e++) {
#pragma unroll
            for (int off = 32; off >= 1; off >>= 1)
                p[e] += __shfl_xor(p[e], off, 64);
        }
        int slot1 = 0, slot2 = 0;
        if (lane == 0) {
            float l[NE];
#pragma unroll
            for (int e = 0; e < NE; e++) {
                l[e] = p[e] + br[e];
                logits_out[(size_t)t * NE + e] = l[e];
            }
            int e1 = 0;
#pragma unroll
            for (int e = 1; e < NE; e++) if (l[e] > l[e1]) e1 = e;
            int es = -1;
#pragma unroll
            for (int e = 0; e < NE; e++) {
                if (e == e1) continue;
                if (es < 0 || l[e] > l[es]) es = e;
            }
            float z = expf(l[es] - l[e1]);
            float inv = 1.f / (1.f + z);
            int pos1 = atomicAdd(&counts[e1 * 16], 1);
            if (pos1 > CAP - 1) pos1 = CAP - 1;
            int pos2 = atomicAdd(&counts[es * 16], 1);
            if (pos2 > CAP - 1) pos2 = CAP - 1;
            slot1 = e1 * CAP + pos1;
            slot2 = es * CAP + pos2;
            pairSlot[t] = make_int2(slot1, slot2);
            pw[t] = make_float2(inv, z * inv);
        }
        slot1 = __shfl(slot1, 0);
        slot2 = __shfl(slot2, 0);
        *reinterpret_cast<short8*>(xg + (size_t)slot1 * DIM + lane * 8) = o;
        *reinterpret_cast<short8*>(xg + (size_t)slot2 * DIM + lane * 8) = o;
    }
}

// ---------------- GEMM1: H = gelu(Xg @ W1^T), per expert | w2 cast tail ----------------
// Block 64m x 128n, K=512 in 4 phases of BK=128. 4 waves (2x2), 48 KB LDS.
// Tail blocks (bx >= GEMM1_BLKS) cast w2 f32->bf16, overlapping gemm1 compute;
// w2b is complete when this grid retires — gemm2 follows in stream order.
__global__ __launch_bounds__(256, 3)
void gemm1(const unsigned short* __restrict__ xg,
           const unsigned short* __restrict__ w1b,
           const int* __restrict__ counts,
           unsigned short* __restrict__ Hb,
           const float* __restrict__ w2,
           unsigned short* __restrict__ w2b) {
    int bx = blockIdx.x;
    int tid = threadIdx.x;
    if (bx >= GEMM1_BLKS) {
        // w2 cast: 16 float4 per thread, 256 blocks x 4096 float4
        int base = (bx - GEMM1_BLKS) * 4096 + tid;
#pragma unroll
        for (int rep = 0; rep < 16; rep++) {
            int j = base + rep * 256;
            float4 v = reinterpret_cast<const float4*>(w2)[j];
            ushort4 o;
            o.x = f2bf_bits(v.x); o.y = f2bf_bits(v.y);
            o.z = f2bf_bits(v.z); o.w = f2bf_bits(v.w);
            reinterpret_cast<ushort4*>(w2b)[j] = o;
        }
        return;
    }
    int e = bx & 7;                       // XCD affinity
    int rest = bx >> 3;
    int n0 = (rest & 7) * 128;
    int m0 = (rest >> 3) * 64;
    int cnt = counts[e * 16]; if (cnt > CAP) cnt = CAP;
    if (m0 >= cnt) return;

    __shared__ __align__(16) unsigned short s_a[64 * 128];    // 16 KB
    __shared__ __align__(16) unsigned short s_b[128 * 128];   // 32 KB

    int wave = tid >> 6, lane = tid & 63;
    int g = lane >> 4, ln = lane & 15;
    int wm = wave & 1, wn = wave >> 1;

    const unsigned short* asrc = xg + (size_t)(e * CAP + m0) * DIM;
    const unsigned short* bsrc = w1b + (size_t)(e * HID + n0) * DIM;

    floatx4 acc[2][4];
#pragma unroll
    for (int mf = 0; mf < 2; mf++)
#pragma unroll
        for (int nf = 0; nf < 4; nf++) acc[mf][nf] = (floatx4){0.f, 0.f, 0.f, 0.f};

    for (int ph = 0; ph < 4; ph++) {
        int k0 = ph * 128;
        stage_tile<64>(asrc, DIM, k0, s_a, wave, lane);
        stage_tile<128>(bsrc, DIM, k0, s_b, wave, lane);
        __syncthreads();
#pragma unroll
        for (int ks = 0; ks < 4; ks++) {
            short8 a0 = frag(s_a, wm * 32 + ln, ks * 4 + g);
            short8 a1 = frag(s_a, wm * 32 + 16 + ln, ks * 4 + g);
#pragma unroll
            for (int nf = 0; nf < 4; nf++) {
                short8 b = frag(s_b, wn * 64 + nf * 16 + ln, ks * 4 + g);
                acc[0][nf] = __builtin_amdgcn_mfma_f32_16x16x32_bf16(a0, b, acc[0][nf], 0, 0, 0);
                acc[1][nf] = __builtin_amdgcn_mfma_f32_16x16x32_bf16(a1, b, acc[1][nf], 0, 0, 0);
            }
        }
        __syncthreads();
    }
#pragma unroll
    for (int mf = 0; mf < 2; mf++)
#pragma unroll
        for (int nf = 0; nf < 4; nf++)
#pragma unroll
            for (int r = 0; r < 4; r++) {
                int lr = wm * 32 + mf * 16 + g * 4 + r;
                int col = n0 + wn * 64 + nf * 16 + ln;
                float v = acc[mf][nf][r];
                float gv = 0.5f * v * (1.f + erff(v * 0.70710678118f));
                Hb[(size_t)(e * CAP + m0 + lr) * HID + col] = f2bf_bits(gv);
            }
}

// ---------------- GEMM2: ybuf[kv] = H @ W2^T (plain stores) ----------------
__global__ __launch_bounds__(256, 3)
void gemm2(const unsigned short* __restrict__ Hb,
           const unsigned short* __restrict__ w2b,
           const int* __restrict__ counts,
           float* __restrict__ ybuf) {
    int bx = blockIdx.x;
    int e = bx & 7;
    int rest = bx >> 3;
    int n0 = (rest & 3) * 128;
    int kv = (rest >> 2) & 1;
    int m0 = (rest >> 3) * 64;
    int cnt = counts[e * 16]; if (cnt > CAP) cnt = CAP;
    if (m0 >= cnt) return;

    __shared__ __align__(16) unsigned short s_a[64 * 128];
    __shared__ __align__(16) unsigned short s_b[128 * 128];

    int tid = threadIdx.x, wave = tid >> 6, lane = tid & 63;
    int g = lane >> 4, ln = lane & 15;
    int wm = wave & 1, wn = wave >> 1;

    const unsigned short* asrc = Hb + (size_t)(e * CAP + m0) * HID;
    const unsigned short* bsrc = w2b + (size_t)(e * DIM + n0) * HID;

    floatx4 acc[2][4];
#pragma unroll
    for (int mf = 0; mf < 2; mf++)
#pragma unroll
        for (int nf = 0; nf < 4; nf++) acc[mf][nf] = (floatx4){0.f, 0.f, 0.f, 0.f};

    for (int ph = 0; ph < 4; ph++) {
        int k0 = kv * 512 + ph * 128;
        stage_tile<64>(asrc, HID, k0, s_a, wave, lane);
        stage_tile<128>(bsrc, HID, k0, s_b, wave, lane);
        __syncthreads();
#pragma unroll
        for (int ks = 0; ks < 4; ks++) {
            short8 a0 = frag(s_a, wm * 32 + ln, ks * 4 + g);
            short8 a1 = frag(s_a, wm * 32 + 16 + ln, ks * 4 + g);
#pragma unroll
            for (int nf = 0; nf < 4; nf++) {
                short8 b = frag(s_b, wn * 64 + nf * 16 + ln, ks * 4 + g);
                acc[0][nf] = __builtin_amdgcn_mfma_f32_16x16x32_bf16(a0, b, acc[0][nf], 0, 0, 0);
                acc[1][nf] = __builtin_amdgcn_mfma_f32_16x16x32_bf16(a1, b, acc[1][nf], 0, 0, 0);
            }
        }
        __syncthreads();
    }
    float* yb = ybuf + (size_t)kv * (NE * CAP * DIM);
#pragma unroll
    for (int mf = 0; mf < 2; mf++)
#pragma unroll
        for (int nf = 0; nf < 4; nf++)
#pragma unroll
            for (int r = 0; r < 4; r++) {
                int lr = wm * 32 + mf * 16 + g * 4 + r;
                int col = n0 + wn * 64 + nf * 16 + ln;
                yb[(size_t)(e * CAP + m0 + lr) * DIM + col] = acc[mf][nf][r];
            }
}

// ---------------- combine ----------------
__global__ __launch_bounds__(256)
void combine_kernel(const float* __restrict__ ybuf, const int2* __restrict__ pairSlot,
                    const float2* __restrict__ pw, float* __restrict__ out) {
    int id = blockIdx.x * 256 + threadIdx.x;   // 262144 = 2048 tokens x 128 float4
    int t = id >> 7, dv = id & 127;
    int2 s = pairSlot[t];
    float2 w = pw[t];
    const size_t KV = (size_t)NE * CAP * DIM;
    const float4* y0a = reinterpret_cast<const float4*>(ybuf + (size_t)s.x * DIM);
    const float4* y1a = reinterpret_cast<const float4*>(ybuf + KV + (size_t)s.x * DIM);
    const float4* y0b = reinterpret_cast<const float4*>(ybuf + (size_t)s.y * DIM);
    const float4* y1b = reinterpret_cast<const float4*>(ybuf + KV + (size_t)s.y * DIM);
    float4 a = y0a[dv], b = y1a[dv], c = y0b[dv], d = y1b[dv];
    float4 r;
    r.x = w.x * (a.x + b.x) + w.y * (c.x + d.x);
    r.y = w.x * (a.y + b.y) + w.y * (c.y + d.y);
    r.z = w.x * (a.z + b.z) + w.y * (c.z + d.z);
    r.w = w.x * (a.w + b.w) + w.y * (c.w + d.w);
    reinterpret_cast<float4*>(out)[(size_t)t * 128 + dv] = r;
}

extern "C" void kernel_launch(void* const* d_in, const int* in_sizes, int n_in,
                              void* d_out, int out_size, void* d_ws, size_t ws_size,
                              hipStream_t stream) {
    const float* x  = (const float*)d_in[0];
    const float* wr = (const float*)d_in[1];
    const float* br = (const float*)d_in[2];
    const float* w1 = (const float*)d_in[3];
    const float* w2 = (const float*)d_in[4];
    float* out = (float*)d_out;
    float* logits_out = out + (size_t)T_TOK * DIM;

    char* ws = (char*)d_ws;
    int*    counts   = (int*)ws;                                // 512 B (x16 padded)
    int2*   pairSlot = (int2*)(ws + 4096);                      // 16 KB
    float2* pw       = (float2*)(ws + 24576);                   // 16 KB
    unsigned short* xg  = (unsigned short*)(ws + 131072);       // 8.4 MB
    unsigned short* w1b = (unsigned short*)(ws + 8519680);      // 8.4 MB
    unsigned short* w2b = (unsigned short*)(ws + 16908288);     // 8.4 MB
    unsigned short* Hb  = (unsigned short*)(ws + 25296896);     // 16.8 MB
    float*          ybuf = (float*)(ws + 42074112);             // 33.6 MB (ends ~76 MB)

    hipMemsetAsync(counts, 0, 512, stream);

    prep<<<ROUT_BLKS + CAST1_BLKS, 256, 0, stream>>>(
        x, wr, br, w1, w1b, xg, counts, pairSlot, pw, logits_out);

    gemm1<<<GEMM1_BLKS + CAST2_BLKS, 256, 0, stream>>>(
        xg, w1b, counts, Hb, w2, w2b);

    gemm2<<<NE * 16 * 2 * 4, 256, 0, stream>>>(Hb, w2b, counts, ybuf);

    combine_kernel<<<1024, 256, 0, stream>>>(ybuf, pairSlot, pw, out);
}